// Round 3
// baseline (482.308 us; speedup 1.0000x reference)
//
#include <hip/hip_runtime.h>
#include <stdint.h>

#define N_TOK 8192
#define DIMD 1024
#define NEXP 8
#define HDIM 2048
#define BKK 64
#define BMT 256                  // M/N tile for both grouped GEMMs
#define MAXT2 72                 // sum ceil(c_e/256) <= 16384/256 + 8
#define MAXROWS2 (MAXT2 * 256)   // 18432 padded row slots

typedef __attribute__((ext_vector_type(8))) short short8;
typedef __attribute__((ext_vector_type(4))) float f32x4;

__device__ __forceinline__ ushort f2bf(float f) {
    uint32_t u = __float_as_uint(f);
    u += 0x7fffu + ((u >> 16) & 1u);   // round-to-nearest-even
    return (ushort)(u >> 16);
}

// global -> LDS direct staging, 16B per lane. LDS dest is wave-uniform base.
__device__ __forceinline__ void gload_lds16(const void* gsrc, void* lds_dst) {
    __builtin_amdgcn_global_load_lds(
        (const __attribute__((address_space(1))) void*)(uintptr_t)(gsrc),
        (__attribute__((address_space(3))) void*)(uintptr_t)(lds_dst),
        16, 0, 0);
}

#define BAR()                              \
    do {                                   \
        __builtin_amdgcn_s_barrier();      \
        __builtin_amdgcn_sched_barrier(0); \
    } while (0)

// One phase's compute quadrant: HIM/HIN are LITERAL constants so acc indexing
// is compile-time (rule #20). 12 ds_read_b128 + 16 MFMA, setprio-wrapped.
#define QUAD(BUF, HIM, HIN)                                                     \
    {                                                                           \
        short8 af[4][2], bfr[2][2];                                             \
        _Pragma("unroll") for (int i2 = 0; i2 < 4; i2++)                        \
            _Pragma("unroll") for (int kk = 0; kk < 2; kk++) {                  \
                int row = wr * 128 + ((HIM) * 4 + i2) * 16 + (lane & 15);       \
                int kb = kk * 64 + ((lane >> 4) * 16);                          \
                af[i2][kk] = *(const short8*)((const char*)&ldsA[BUF][0] +      \
                              row * 128 + (kb ^ ((row & 7) << 4)));             \
            }                                                                   \
        _Pragma("unroll") for (int j2 = 0; j2 < 2; j2++)                        \
            _Pragma("unroll") for (int kk = 0; kk < 2; kk++) {                  \
                int row = wc * 64 + ((HIN) * 2 + j2) * 16 + (lane & 15);        \
                int kb = kk * 64 + ((lane >> 4) * 16);                          \
                bfr[j2][kk] = *(const short8*)((const char*)&ldsB[BUF][0] +     \
                              row * 128 + (kb ^ ((row & 7) << 4)));             \
            }                                                                   \
        __builtin_amdgcn_s_setprio(1);                                          \
        _Pragma("unroll") for (int i2 = 0; i2 < 4; i2++)                        \
            _Pragma("unroll") for (int j2 = 0; j2 < 2; j2++)                    \
                _Pragma("unroll") for (int kk = 0; kk < 2; kk++)                \
                    acc[(HIM) * 4 + i2][(HIN) * 2 + j2] =                       \
                        __builtin_amdgcn_mfma_f32_16x16x32_bf16(                \
                            af[i2][kk], bfr[j2][kk],                            \
                            acc[(HIM) * 4 + i2][(HIN) * 2 + j2], 0, 0, 0);      \
        __builtin_amdgcn_s_setprio(0);                                          \
    }

// ---------------- conversion kernels ----------------

__global__ void conv_x_kernel(const float* __restrict__ x, ushort* __restrict__ xb) {
    int i = blockIdx.x * blockDim.x + threadIdx.x;
    int base = i * 8;
    const float4* p = (const float4*)(x + base);
    float4 a = p[0], b = p[1];
    alignas(16) ushort tmp[8];
    tmp[0] = f2bf(a.x); tmp[1] = f2bf(a.y); tmp[2] = f2bf(a.z); tmp[3] = f2bf(a.w);
    tmp[4] = f2bf(b.x); tmp[5] = f2bf(b.y); tmp[6] = f2bf(b.z); tmp[7] = f2bf(b.w);
    *(short8*)(xb + base) = *(const short8*)tmp;
}

// in: [E][R][C] f32 -> out: [E][C][R] bf16  (transpose so K becomes contiguous)
__global__ void transpose_cvt(const float* __restrict__ in, ushort* __restrict__ out,
                              int R, int C) {
    __shared__ float t[32][33];
    int e = blockIdx.x, r0 = blockIdx.y * 32, c0 = blockIdx.z * 32;
    const float* pin = in + (size_t)e * R * C;
    ushort* pout = out + (size_t)e * R * C;
    int c = threadIdx.x & 31, g = threadIdx.x >> 5;
#pragma unroll
    for (int i = 0; i < 4; i++) {
        int r = g + i * 8;
        t[r][c] = pin[(size_t)(r0 + r) * C + c0 + c];
    }
    __syncthreads();
#pragma unroll
    for (int i = 0; i < 4; i++) {
        int cc = g + i * 8;
        pout[(size_t)(c0 + cc) * R + r0 + c] = f2bf(t[c][cc]);
    }
}

// ---------------- gate ----------------

__global__ void gate_kernel(const float* __restrict__ x, const float* __restrict__ gw,
                            const float* __restrict__ gb, int* __restrict__ topi,
                            float* __restrict__ topw, int* __restrict__ counts,
                            float* __restrict__ probsum) {
    __shared__ float ps[NEXP];
    __shared__ int cs[NEXP];
    int tid = threadIdx.x;
    if (tid < NEXP) { ps[tid] = 0.f; cs[tid] = 0; }
    __syncthreads();
    int wid = tid >> 6, lane = tid & 63;
    int n = blockIdx.x * 4 + wid;
    const float* xr = x + (size_t)n * DIMD;
    float acc[NEXP];
#pragma unroll
    for (int e = 0; e < NEXP; e++) acc[e] = 0.f;
    for (int i = 0; i < DIMD / 64; i++) {
        int c = lane + i * 64;
        float xv = xr[c];
        const float* g = gw + (size_t)c * NEXP;
#pragma unroll
        for (int e = 0; e < NEXP; e++) acc[e] += xv * g[e];
    }
#pragma unroll
    for (int e = 0; e < NEXP; e++) {
        float v = acc[e];
#pragma unroll
        for (int off = 32; off > 0; off >>= 1) v += __shfl_xor(v, off);
        acc[e] = v + gb[e];
    }
    float m = acc[0];
#pragma unroll
    for (int e = 1; e < NEXP; e++) m = fmaxf(m, acc[e]);
    float p[NEXP], s = 0.f;
#pragma unroll
    for (int e = 0; e < NEXP; e++) { p[e] = expf(acc[e] - m); s += p[e]; }
    int e1 = 0;
#pragma unroll
    for (int e = 1; e < NEXP; e++) if (p[e] > p[e1]) e1 = e;
    int e2 = (e1 == 0) ? 1 : 0;
#pragma unroll
    for (int e = 0; e < NEXP; e++) if (e != e1 && p[e] > p[e2]) e2 = e;
    float wa = p[e1] / (p[e1] + p[e2]);
    if (lane == 0) {
        topi[n * 2] = e1; topi[n * 2 + 1] = e2;
        topw[n * 2] = wa; topw[n * 2 + 1] = 1.f - wa;
        atomicAdd(&cs[e1], 1); atomicAdd(&cs[e2], 1);
        float inv = 1.f / s;
#pragma unroll
        for (int e = 0; e < NEXP; e++) atomicAdd(&ps[e], p[e] * inv);
    }
    __syncthreads();
    if (tid < NEXP) { atomicAdd(&probsum[tid], ps[tid]); atomicAdd(&counts[tid], cs[tid]); }
}

// ---------------- routing ----------------

__global__ void plan_kernel(const int* __restrict__ counts, int* __restrict__ pbase,
                            int2* __restrict__ tiles, int* __restrict__ ntiles) {
    if (threadIdx.x != 0) return;
    int slot = 0, t = 0;
    for (int e = 0; e < NEXP; e++) {
        pbase[e] = slot;
        int nt = (counts[e] + BMT - 1) / BMT;
        for (int i = 0; i < nt; i++) { tiles[t] = make_int2(e, slot + i * BMT); t++; }
        slot += nt * BMT;
    }
    *ntiles = t;
}

__global__ void init_rows_kernel(int* __restrict__ row_token, float* __restrict__ row_weight) {
    int i = blockIdx.x * blockDim.x + threadIdx.x;
    if (i < MAXROWS2) { row_token[i] = 0; row_weight[i] = 0.f; }
}

__global__ void scatter_kernel(const int* __restrict__ topi, const float* __restrict__ topw,
                               const int* __restrict__ pbase, int* __restrict__ cursor,
                               int* __restrict__ row_token, float* __restrict__ row_weight) {
    __shared__ int lcnt[NEXP], lbase[NEXP];
    int t = blockIdx.x * 256 + threadIdx.x;
    if (threadIdx.x < NEXP) lcnt[threadIdx.x] = 0;
    __syncthreads();
    int e = topi[t];
    int lpos = atomicAdd(&lcnt[e], 1);
    __syncthreads();
    if (threadIdx.x < NEXP) lbase[threadIdx.x] = atomicAdd(&cursor[threadIdx.x], lcnt[threadIdx.x]);
    __syncthreads();
    int pos = pbase[e] + lbase[e] + lpos;
    row_token[pos] = t >> 1;
    row_weight[pos] = topw[t];
}

// ---------------- grouped GEMMs: 256x256 tile, BK=64, 8 waves, 8-phase ----------------
// Staging chunks per K-tile: A0..A3, B0..B3 (64 rows x 64 K each, 8KB, 2 gload/thread... 
// one gload per thread per chunk; block of 512 threads covers a chunk per instruction).
// Issue order (for next K-tile): p0:{A0,A2} p1:{B0,B1} p2:{B2,B3} p3:{A1,A3}.
// Needed-at: p0/p1 need prev A0,A2,B0..B3 ; p2/p3 need prev A1,A3.
// Counted waits: p0 -> vmcnt(4) [allow prev A1,A3 + cur p0's 2]
//                p2 -> vmcnt(6) [allow cur p0+p1+p2 = 6]
// Peeled last tile (no staging): p0 -> vmcnt(2), p2 -> vmcnt(0).

__global__ __launch_bounds__(512, 2) void gemm1_kernel(
        const ushort* __restrict__ xb, const ushort* __restrict__ w1t,
        const float* __restrict__ b1, ushort* __restrict__ hbuf,
        const int* __restrict__ row_token, const int2* __restrict__ tiles,
        const int* __restrict__ ntiles) {
    int tm = blockIdx.x;
    if (tm >= *ntiles) return;
    int e = tiles[tm].x;
    int slotbase = tiles[tm].y;
    int nbase = blockIdx.y * BMT;
    __shared__ alignas(16) ushort ldsA[2][BMT * BKK];
    __shared__ alignas(16) ushort ldsB[2][BMT * BKK];
    int tid = threadIdx.x, lane = tid & 63, wid = tid >> 6;
    int wr = wid >> 2, wc = wid & 3;
    f32x4 acc[8][4];
#pragma unroll
    for (int i = 0; i < 8; i++)
#pragma unroll
        for (int j = 0; j < 4; j++) acc[i][j] = (f32x4){0.f, 0.f, 0.f, 0.f};

    int trow = tid >> 3;                                           // 0..63
    int scol = ((((tid & 7) * 16) ^ ((trow & 7) << 4)) >> 1);      // ushort units
    int tok[4];
#pragma unroll
    for (int n = 0; n < 4; n++) tok[n] = row_token[slotbase + n * 64 + trow];
    const ushort* bmat = w1t + (size_t)e * HDIM * DIMD;

#define STAGE_A1(BUF, n, k0)                                                   \
    gload_lds16(xb + (size_t)tok[n] * DIMD + (k0) + scol,                      \
                &ldsA[BUF][(n) * 4096 + wid * 512])
#define STAGE_B1(BUF, n, k0)                                                   \
    gload_lds16(bmat + (size_t)(nbase + (n) * 64 + trow) * DIMD + (k0) + scol, \
                &ldsB[BUF][(n) * 4096 + wid * 512])

    // prologue: stage K-tile 0 into buf 0, order A0,A2,B0,B1,B2,B3,A1,A3
    STAGE_A1(0, 0, 0); STAGE_A1(0, 2, 0);
    STAGE_B1(0, 0, 0); STAGE_B1(0, 1, 0); STAGE_B1(0, 2, 0); STAGE_B1(0, 3, 0);
    STAGE_A1(0, 1, 0); STAGE_A1(0, 3, 0);

    const int NT = DIMD / BKK;   // 16
    int bb = 0;
    for (int kt = 0; kt < NT - 1; kt++) {
        int k1 = (kt + 1) * BKK;
        STAGE_A1(bb ^ 1, 0, k1); STAGE_A1(bb ^ 1, 2, k1);
        asm volatile("s_waitcnt vmcnt(4)" ::: "memory");
        BAR(); QUAD(bb, 0, 0); BAR();
        STAGE_B1(bb ^ 1, 0, k1); STAGE_B1(bb ^ 1, 1, k1);
        BAR(); QUAD(bb, 0, 1); BAR();
        STAGE_B1(bb ^ 1, 2, k1); STAGE_B1(bb ^ 1, 3, k1);
        asm volatile("s_waitcnt vmcnt(6)" ::: "memory");
        BAR(); QUAD(bb, 1, 0); BAR();
        STAGE_A1(bb ^ 1, 1, k1); STAGE_A1(bb ^ 1, 3, k1);
        BAR(); QUAD(bb, 1, 1); BAR();
        bb ^= 1;
    }
    asm volatile("s_waitcnt vmcnt(2)" ::: "memory");
    BAR(); QUAD(bb, 0, 0); BAR();
    BAR(); QUAD(bb, 0, 1); BAR();
    asm volatile("s_waitcnt vmcnt(0)" ::: "memory");
    BAR(); QUAD(bb, 1, 0); BAR();
    BAR(); QUAD(bb, 1, 1); BAR();
#undef STAGE_A1
#undef STAGE_B1

    const float* b1e = b1 + (size_t)e * HDIM;
#pragma unroll
    for (int im = 0; im < 8; im++) {
#pragma unroll
        for (int in = 0; in < 4; in++) {
            int col = nbase + wc * 64 + in * 16 + (lane & 15);
            float bias = b1e[col];
#pragma unroll
            for (int r = 0; r < 4; r++) {
                int row = slotbase + wr * 128 + im * 16 + (lane >> 4) * 4 + r;
                float v = fmaxf(acc[im][in][r] + bias, 0.f);
                hbuf[(size_t)row * HDIM + col] = f2bf(v);
            }
        }
    }
}

__global__ __launch_bounds__(512, 2) void gemm2_kernel(
        const ushort* __restrict__ hbuf, const ushort* __restrict__ w2t,
        const float* __restrict__ b2, float* __restrict__ outp,
        const int* __restrict__ row_token, const float* __restrict__ row_weight,
        const int2* __restrict__ tiles, const int* __restrict__ ntiles) {
    int tm = blockIdx.x;
    if (tm >= *ntiles) return;
    int e = tiles[tm].x;
    int slotbase = tiles[tm].y;
    int nbase = blockIdx.y * BMT;
    __shared__ alignas(16) ushort ldsA[2][BMT * BKK];
    __shared__ alignas(16) ushort ldsB[2][BMT * BKK];
    int tid = threadIdx.x, lane = tid & 63, wid = tid >> 6;
    int wr = wid >> 2, wc = wid & 3;
    f32x4 acc[8][4];
#pragma unroll
    for (int i = 0; i < 8; i++)
#pragma unroll
        for (int j = 0; j < 4; j++) acc[i][j] = (f32x4){0.f, 0.f, 0.f, 0.f};

    int trow = tid >> 3;
    int scol = ((((tid & 7) * 16) ^ ((trow & 7) << 4)) >> 1);
    const ushort* amat = hbuf + (size_t)slotbase * HDIM;
    const ushort* bmat = w2t + (size_t)e * DIMD * HDIM;

#define STAGE_A2(BUF, n, k0)                                                   \
    gload_lds16(amat + (size_t)((n) * 64 + trow) * HDIM + (k0) + scol,         \
                &ldsA[BUF][(n) * 4096 + wid * 512])
#define STAGE_B2(BUF, n, k0)                                                   \
    gload_lds16(bmat + (size_t)(nbase + (n) * 64 + trow) * HDIM + (k0) + scol, \
                &ldsB[BUF][(n) * 4096 + wid * 512])

    STAGE_A2(0, 0, 0); STAGE_A2(0, 2, 0);
    STAGE_B2(0, 0, 0); STAGE_B2(0, 1, 0); STAGE_B2(0, 2, 0); STAGE_B2(0, 3, 0);
    STAGE_A2(0, 1, 0); STAGE_A2(0, 3, 0);

    const int NT = HDIM / BKK;   // 32
    int bb = 0;
    for (int kt = 0; kt < NT - 1; kt++) {
        int k1 = (kt + 1) * BKK;
        STAGE_A2(bb ^ 1, 0, k1); STAGE_A2(bb ^ 1, 2, k1);
        asm volatile("s_waitcnt vmcnt(4)" ::: "memory");
        BAR(); QUAD(bb, 0, 0); BAR();
        STAGE_B2(bb ^ 1, 0, k1); STAGE_B2(bb ^ 1, 1, k1);
        BAR(); QUAD(bb, 0, 1); BAR();
        STAGE_B2(bb ^ 1, 2, k1); STAGE_B2(bb ^ 1, 3, k1);
        asm volatile("s_waitcnt vmcnt(6)" ::: "memory");
        BAR(); QUAD(bb, 1, 0); BAR();
        STAGE_A2(bb ^ 1, 1, k1); STAGE_A2(bb ^ 1, 3, k1);
        BAR(); QUAD(bb, 1, 1); BAR();
        bb ^= 1;
    }
    asm volatile("s_waitcnt vmcnt(2)" ::: "memory");
    BAR(); QUAD(bb, 0, 0); BAR();
    BAR(); QUAD(bb, 0, 1); BAR();
    asm volatile("s_waitcnt vmcnt(0)" ::: "memory");
    BAR(); QUAD(bb, 1, 0); BAR();
    BAR(); QUAD(bb, 1, 1); BAR();
#undef STAGE_A2
#undef STAGE_B2

    const float* b2e = b2 + (size_t)e * DIMD;
#pragma unroll
    for (int im = 0; im < 8; im++) {
#pragma unroll
        for (int r = 0; r < 4; r++) {
            int srow = slotbase + wr * 128 + im * 16 + (lane >> 4) * 4 + r;
            int token = row_token[srow];
            float w = row_weight[srow];
            float* orow = outp + (size_t)token * DIMD;
#pragma unroll
            for (int in = 0; in < 4; in++) {
                int col = nbase + wc * 64 + in * 16 + (lane & 15);
                float v = acc[im][in][r] + b2e[col];
                atomicAdd(&orow[col], w * v);
            }
        }
    }
}

__global__ void finalize_kernel(const float* __restrict__ probsum, const int* __restrict__ counts,
                                float* __restrict__ loss_out) {
    if (threadIdx.x == 0) {
        float l = 0.f;
        for (int e = 0; e < NEXP; e++) l += probsum[e] * (float)counts[e];
        *loss_out = l / ((float)N_TOK * (float)N_TOK);
    }
}

// ---------------- launch ----------------

extern "C" void kernel_launch(void* const* d_in, const int* in_sizes, int n_in,
                              void* d_out, int out_size, void* d_ws, size_t ws_size,
                              hipStream_t stream) {
    const float* x      = (const float*)d_in[0];
    const float* gate_w = (const float*)d_in[1];
    const float* gate_b = (const float*)d_in[2];
    const float* w1     = (const float*)d_in[3];
    const float* b1     = (const float*)d_in[4];
    const float* w2     = (const float*)d_in[5];
    const float* b2     = (const float*)d_in[6];
    float* outp = (float*)d_out;

    char* ws = (char*)d_ws;
    ushort* xb   = (ushort*)(ws);                 // 16.8 MB
    ushort* w1t  = (ushort*)(ws + 16777216);      // 33.6 MB  [E][H][D] bf16
    ushort* w2t  = (ushort*)(ws + 50331648);      // 33.6 MB  [E][D][H] bf16
    ushort* hbuf = (ushort*)(ws + 83886080);      // 75.5 MB  [MAXROWS2][H] bf16
    char* ctrl   = ws + 159383552;
    int*   counts     = (int*)(ctrl + 0);
    int*   cursor     = (int*)(ctrl + 32);
    float* probsum    = (float*)(ctrl + 64);
    int*   ntiles     = (int*)(ctrl + 96);
    int*   pbase      = (int*)(ctrl + 128);
    int2*  tiles      = (int2*)(ctrl + 160);      // 72*8 = 576 B
    int*   topi       = (int*)(ctrl + 2048);
    float* topw       = (float*)(ctrl + 2048 + 65536);
    int*   row_token  = (int*)(ctrl + 2048 + 131072);
    float* row_weight = (float*)(ctrl + 2048 + 131072 + 73728);

    hipMemsetAsync(ctrl, 0, 128, stream);
    hipMemsetAsync(d_out, 0, (size_t)out_size * sizeof(float), stream);

    conv_x_kernel<<<4096, 256, 0, stream>>>(x, xb);
    transpose_cvt<<<dim3(NEXP, DIMD / 32, HDIM / 32), 256, 0, stream>>>(w1, w1t, DIMD, HDIM);
    transpose_cvt<<<dim3(NEXP, HDIM / 32, DIMD / 32), 256, 0, stream>>>(w2, w2t, HDIM, DIMD);
    gate_kernel<<<N_TOK / 4, 256, 0, stream>>>(x, gate_w, gate_b, topi, topw, counts, probsum);
    plan_kernel<<<1, 64, 0, stream>>>(counts, pbase, tiles, ntiles);
    init_rows_kernel<<<MAXROWS2 / 256, 256, 0, stream>>>(row_token, row_weight);
    scatter_kernel<<<(N_TOK * 2) / 256, 256, 0, stream>>>(topi, topw, pbase, cursor,
                                                          row_token, row_weight);
    gemm1_kernel<<<dim3(MAXT2, HDIM / BMT), 512, 0, stream>>>(xb, w1t, b1, hbuf,
                                                              row_token, tiles, ntiles);
    gemm2_kernel<<<dim3(MAXT2, DIMD / BMT), 512, 0, stream>>>(hbuf, w2t, b2, outp,
                                                              row_token, row_weight, tiles, ntiles);
    finalize_kernel<<<1, 64, 0, stream>>>(probsum, counts, outp + (size_t)N_TOK * DIMD);
}